// Round 16
// baseline (70.081 us; speedup 1.0000x reference)
//
#include <hip/hip_runtime.h>

#define NB 64
#define NN 4096
#define NC 128
#define NH 4
#define HC (NH * NC)        // 512
#define PSTRIDE (8 + HC)    // 520 floats per partial: [4 pad][4 L][512 S]
#define NSLICE 16           // 16*64 = 1024 blocks
#define TROWS 64            // rows per LDS tile (32 KB)
#define LRELU 0.2f

// ---------------- k0: wt[k][h] = sum_c W[k, h*C+c] * t[h,c];  bt[h] = sum_c bias*t.
__global__ __launch_bounds__(128) void k0_wt(const float* __restrict__ W,
                                             const float* __restrict__ bias,
                                             const float* __restrict__ tune,
                                             float* __restrict__ wtbt)
{
    const int bid = blockIdx.x;
    const int t = threadIdx.x;                       // 0..127
    const float* src = (bid < NC) ? (W + (size_t)bid * HC) : bias;
    float* dst = (bid < NC) ? (wtbt + bid * NH) : (wtbt + NC * NH);
    const float4 a = reinterpret_cast<const float4*>(src)[t];
    const float4 b = reinterpret_cast<const float4*>(tune)[t];
    float p = a.x * b.x + a.y * b.y + a.z * b.z + a.w * b.w;
    #pragma unroll
    for (int off = 16; off; off >>= 1) p += __shfl_xor(p, off, 32);
    if ((t & 31) == 0) dst[t >> 5] = p;              // group t>>5 == head h
}

// ---------------- k1: grid (NSLICE, NB). Block owns contiguous rows
// [slice*segB, min(+segB, gs)). LDS-staged with ASYNC-STAGE SPLIT (T14):
// per tile: {ds_write regs(t) -> barrier -> ISSUE global loads(t+1) -> compute(t)
// from LDS -> barrier}. Next tile's loads fly under this tile's compute, so the
// global->LDS round trip is hidden; the only waiter is next iteration's ds_write.
__global__ __launch_bounds__(256, 4) void k1_part(const float* __restrict__ V,
                                                  const int* __restrict__ gs,
                                                  const float* __restrict__ wtbt,
                                                  float* __restrict__ part)
{
    __shared__ float smem[8192];                     // 32 KB, unioned
    float (*Vt)[NC] = reinterpret_cast<float(*)[NC]>(smem);          // [64][128]
    float (*Sall)[NH][132] = reinterpret_cast<float(*)[NH][132]>(smem); // [8][4][132]
    float* llds = smem + 8 * NH * 132;               // 32 floats

    const int slice = blockIdx.x;
    const int b = blockIdx.y;
    const int tid = threadIdx.x;
    const int hw = tid >> 5;          // half-wave 0..7
    const int lane = tid & 31;
    const int h = lane >> 3;          // head 0..3
    const int j = lane & 7;           // feature-group (features 16j..16j+15)
    const int gsz = gs[b];

    float wtk[16];
    #pragma unroll
    for (int u = 0; u < 16; ++u) wtk[u] = wtbt[(16 * j + u) * NH + h];
    const float bt = wtbt[HC + h];

    const int segB = (gsz + NSLICE - 1) / NSLICE;    // rows per block
    const int myBeg = slice * segB;
    int myEnd = myBeg + segB;
    if (myEnd > gsz) myEnd = gsz;
    const int nrows = (myEnd > myBeg) ? (myEnd - myBeg) : 0;
    const int ntile = (nrows + TROWS - 1) / TROWS;

    float l = 0.f;
    float S[16] = {};

    const float4* Vg4 = reinterpret_cast<const float4*>(V);
    const size_t gbase = (size_t)b * NN;

    // ---- prologue: issue tile 0's loads into regs
    float4 r[8];
    if (ntile > 0) {
        #pragma unroll
        for (int k = 0; k < 8; ++k) {
            const int idx = tid + (k << 8);
            const int gr = myBeg + (idx >> 5);
            const int src_row = (gr < myEnd) ? gr : myBeg;
            r[k] = Vg4[(gbase + src_row) * 32 + (idx & 31)];
        }
    }

    for (int tile = 0; tile < ntile; ++tile) {
        const int tbase = myBeg + tile * TROWS;
        // ---- write THIS tile's regs to LDS (waits only on its own loads,
        //      which have had a full compute phase to land)
        #pragma unroll
        for (int k = 0; k < 8; ++k) {
            const int idx = tid + (k << 8);
            reinterpret_cast<float4*>(smem)[idx] = r[k];
        }
        __syncthreads();
        // ---- ISSUE next tile's loads now; they fly under the compute below
        {
            const int nbase = tbase + TROWS;
            #pragma unroll
            for (int k = 0; k < 8; ++k) {
                const int idx = tid + (k << 8);
                const int gr = nbase + (idx >> 5);
                const int src_row = (gr < myEnd) ? gr : myBeg;   // clamped (tail-safe)
                r[k] = Vg4[(gbase + src_row) * 32 + (idx & 31)];
            }
        }
        // ---- compute THIS tile from LDS: half-wave hw owns rows hw*8..hw*8+7
        #pragma unroll 2
        for (int rr = 0; rr < 8; ++rr) {
            const int row = (hw << 3) + rr;
            const bool valid = (tbase + row < myEnd);
            const float4* vr = reinterpret_cast<const float4*>(&Vt[row][j * 16]);
            const float4 A0 = vr[0];
            const float4 A1 = vr[1];
            const float4 A2 = vr[2];
            const float4 A3 = vr[3];
            float a0 = A0.x * wtk[0]  + A0.y * wtk[1]  + A0.z * wtk[2]  + A0.w * wtk[3];
            float a1 = A1.x * wtk[4]  + A1.y * wtk[5]  + A1.z * wtk[6]  + A1.w * wtk[7];
            float a2 = A2.x * wtk[8]  + A2.y * wtk[9]  + A2.z * wtk[10] + A2.w * wtk[11];
            float a3 = A3.x * wtk[12] + A3.y * wtk[13] + A3.z * wtk[14] + A3.w * wtk[15];
            float lg = (a0 + a1) + (a2 + a3);
            lg += __shfl_xor(lg, 1, 32);
            lg += __shfl_xor(lg, 2, 32);
            lg += __shfl_xor(lg, 4, 32);   // 8-lane head group holds full logit
            float x = lg + bt;
            x = (x >= 0.f) ? x : LRELU * x;           // leaky_relu
            float p = __expf(x);                      // no max subtraction
            p = valid ? p : 0.f;
            l += p;
            S[0]  += p * A0.x;  S[1]  += p * A0.y;  S[2]  += p * A0.z;  S[3]  += p * A0.w;
            S[4]  += p * A1.x;  S[5]  += p * A1.y;  S[6]  += p * A1.z;  S[7]  += p * A1.w;
            S[8]  += p * A2.x;  S[9]  += p * A2.y;  S[10] += p * A2.z;  S[11] += p * A2.w;
            S[12] += p * A3.x;  S[13] += p * A3.y;  S[14] += p * A3.z;  S[15] += p * A3.w;
        }
        __syncthreads();                              // Vt reusable next iteration
    }

    // ---- block combine across 8 half-waves (smem reused: Sall/llds)
    if (j == 0) llds[hw * NH + h] = l;
    #pragma unroll
    for (int t = 0; t < 4; ++t) {
        float4 s4;
        s4.x = S[4 * t]; s4.y = S[4 * t + 1]; s4.z = S[4 * t + 2]; s4.w = S[4 * t + 3];
        *reinterpret_cast<float4*>(&Sall[hw][h][16 * j + 4 * t]) = s4;
    }
    __syncthreads();
    float* pb = part + (size_t)(b * NSLICE + slice) * PSTRIDE;
    if (tid < 4) {
        float L = 0.f;
        #pragma unroll
        for (int ww = 0; ww < 8; ++ww) L += llds[ww * NH + tid];
        pb[4 + tid] = L;
    }
    #pragma unroll
    for (int r2 = 0; r2 < 2; ++r2) {
        const int e = tid + r2 * 256;
        const int hh = e >> 7, k = e & 127;
        float s = 0.f;
        #pragma unroll
        for (int ww = 0; ww < 8; ++ww) s += Sall[ww][hh][k];
        pb[8 + e] = s;
    }
}

// ---------------- k2: block (b, h): merge NSLICE partials for head h, then
// out[b, h*128+d] = (S[h]/L[h]) . W[:, h*128+d] + bias[h*128+d]
__global__ __launch_bounds__(128) void k2_out(const float* __restrict__ part,
                                              const float* __restrict__ W,
                                              const float* __restrict__ bias,
                                              float* __restrict__ out)
{
    const int b = blockIdx.x;
    const int h = blockIdx.y;
    const int tid = threadIdx.x;     // 0..127
    const float* pb = part + (size_t)b * NSLICE * PSTRIDE;

    __shared__ float Sn[NC];
    __shared__ float sL;
    if (tid == 0) {
        float L = 0.f;
        #pragma unroll
        for (int c = 0; c < NSLICE; ++c) L += pb[(size_t)c * PSTRIDE + 4 + h];
        sL = L;
    }
    __syncthreads();
    {
        float s = 0.f;
        #pragma unroll 4
        for (int c = 0; c < NSLICE; ++c)
            s += pb[(size_t)c * PSTRIDE + 8 + h * NC + tid];
        Sn[tid] = s / sL;
    }
    __syncthreads();
    const int d = h * NC + tid;
    float acc = 0.f;
    #pragma unroll 4
    for (int k = 0; k < NC; ++k) acc += Sn[k] * W[(size_t)k * HC + d];
    out[(size_t)b * HC + d] = acc + bias[d];
}

extern "C" void kernel_launch(void* const* d_in, const int* in_sizes, int n_in,
                              void* d_out, int out_size, void* d_ws, size_t ws_size,
                              hipStream_t stream)
{
    const float* V    = (const float*)d_in[0];
    const int*   gsz  = (const int*)d_in[1];
    const float* W    = (const float*)d_in[2];
    const float* bias = (const float*)d_in[3];
    const float* tune = (const float*)d_in[4];
    float* out  = (float*)d_out;
    float* wtbt = (float*)d_ws;            // 520 floats (516 used)
    float* part = wtbt + PSTRIDE;          // NB*NSLICE*PSTRIDE floats (~2.1 MB)

    hipLaunchKernelGGL(k0_wt, dim3(NC + 1), dim3(128), 0, stream, W, bias, tune, wtbt);
    hipLaunchKernelGGL(k1_part, dim3(NSLICE, NB), dim3(256), 0, stream, V, gsz, wtbt, part);
    hipLaunchKernelGGL(k2_out, dim3(NB, NH), dim3(128), 0, stream, part, W, bias, out);
}

// Round 17
// 46.514 us; speedup vs baseline: 1.5067x; 1.5067x over previous
//
#include <hip/hip_runtime.h>

#define NB 64
#define NN 4096
#define NC 128
#define NH 4
#define HC (NH * NC)        // 512
#define NSLICE 16           // 16*64 = 1024 blocks
#define TROWS 64            // rows per LDS tile (32 KB)
#define LRELU 0.2f

// ws float layout: [0,520) wtbt | [520,584) cnt (64 ints) | [584,840) Lacc | [840,33608) Sacc
#define WS_CNT  520
#define WS_LACC 584
#define WS_SACC 840
#define WS_ZWORDS (64 + 256 + NB * HC)   // words to zero starting at WS_CNT

// ---------------- k0: wt[k][h] = sum_c W[k, h*C+c]*t[h,c]; bt[h] = sum_c bias*t.
// Also zeroes cnt/Lacc/Sacc every call (fresh accumulators per launch).
__global__ __launch_bounds__(128) void k0_wt(const float* __restrict__ W,
                                             const float* __restrict__ bias,
                                             const float* __restrict__ tune,
                                             float* __restrict__ ws)
{
    const int bid = blockIdx.x;
    const int t = threadIdx.x;                       // 0..127
    // grid-stride zero of accumulators (129*128 = 16512 threads, 33088 words)
    for (int idx = bid * 128 + t; idx < WS_ZWORDS; idx += 129 * 128)
        ws[WS_CNT + idx] = 0.f;
    const float* src = (bid < NC) ? (W + (size_t)bid * HC) : bias;
    float* dst = (bid < NC) ? (ws + bid * NH) : (ws + NC * NH);
    const float4 a = reinterpret_cast<const float4*>(src)[t];
    const float4 b = reinterpret_cast<const float4*>(tune)[t];
    float p = a.x * b.x + a.y * b.y + a.z * b.z + a.w * b.w;
    #pragma unroll
    for (int off = 16; off; off >>= 1) p += __shfl_xor(p, off, 32);
    if ((t & 31) == 0) dst[t >> 5] = p;              // group t>>5 == head h
}

// ---------------- kFused: r15's LDS-staged k1 loop VERBATIM, then atomic-add merge
// into per-graph (Lacc, Sacc); 16th block of each graph (atomic counter) re-reads the
// accumulators coherently (atomicAdd(p,0)) and does normalize + output GEMV.
// No __threadfence anywhere (atomics are L2-coherent; __syncthreads drains vmcnt).
__global__ __launch_bounds__(256, 4) void kfused(const float* __restrict__ V,
                                                 const int* __restrict__ gs,
                                                 float* __restrict__ ws,
                                                 const float* __restrict__ W,
                                                 const float* __restrict__ bias,
                                                 float* __restrict__ out)
{
    __shared__ float smem[8192];                     // 32 KB, unioned
    float (*Vt)[NC] = reinterpret_cast<float(*)[NC]>(smem);          // [64][128]
    float (*Sall)[NH][132] = reinterpret_cast<float(*)[NH][132]>(smem); // [8][4][132]
    float* llds = smem + 8 * NH * 132;               // 32 floats
    __shared__ int   sOld;
    __shared__ float Lh[NH];

    const float* wtbt = ws;
    int*   cnt  = reinterpret_cast<int*>(ws + WS_CNT);
    float* Lacc = ws + WS_LACC;
    float* Sacc = ws + WS_SACC;

    const int slice = blockIdx.x;
    const int b = blockIdx.y;
    const int tid = threadIdx.x;
    const int hw = tid >> 5;          // half-wave 0..7
    const int lane = tid & 31;
    const int h = lane >> 3;          // head 0..3
    const int j = lane & 7;           // feature-group (features 16j..16j+15)
    const int gsz = gs[b];

    float wtk[16];
    #pragma unroll
    for (int u = 0; u < 16; ++u) wtk[u] = wtbt[(16 * j + u) * NH + h];
    const float bt = wtbt[HC + h];

    const int segB = (gsz + NSLICE - 1) / NSLICE;    // rows per block
    const int myBeg = slice * segB;
    int myEnd = myBeg + segB;
    if (myEnd > gsz) myEnd = gsz;
    const int nrows = (myEnd > myBeg) ? (myEnd - myBeg) : 0;
    const int ntile = (nrows + TROWS - 1) / TROWS;

    float l = 0.f;
    float S[16] = {};

    const float4* Vg4 = reinterpret_cast<const float4*>(V);
    const size_t gbase = (size_t)b * NN;

    for (int tile = 0; tile < ntile; ++tile) {
        const int tbase = myBeg + tile * TROWS;
        // ---- stage: 2048 float4; thread t does idx = t + 256k (8 independent loads)
        float4 r[8];
        #pragma unroll
        for (int k = 0; k < 8; ++k) {
            const int idx = tid + (k << 8);
            const int row = idx >> 5;                 // 0..63
            const int gr = tbase + row;
            const int src_row = (gr < myEnd) ? gr : myBeg;   // clamp (masked later)
            r[k] = Vg4[(gbase + src_row) * 32 + (idx & 31)];
        }
        #pragma unroll
        for (int k = 0; k < 8; ++k) {
            const int idx = tid + (k << 8);
            reinterpret_cast<float4*>(smem)[idx] = r[k];
        }
        __syncthreads();
        // ---- compute: half-wave hw handles rows hw*8 .. hw*8+7 from LDS
        #pragma unroll 2
        for (int rr = 0; rr < 8; ++rr) {
            const int row = (hw << 3) + rr;
            const bool valid = (tbase + row < myEnd);
            const float4* vr = reinterpret_cast<const float4*>(&Vt[row][j * 16]);
            const float4 A0 = vr[0];
            const float4 A1 = vr[1];
            const float4 A2 = vr[2];
            const float4 A3 = vr[3];
            float a0 = A0.x * wtk[0]  + A0.y * wtk[1]  + A0.z * wtk[2]  + A0.w * wtk[3];
            float a1 = A1.x * wtk[4]  + A1.y * wtk[5]  + A1.z * wtk[6]  + A1.w * wtk[7];
            float a2 = A2.x * wtk[8]  + A2.y * wtk[9]  + A2.z * wtk[10] + A2.w * wtk[11];
            float a3 = A3.x * wtk[12] + A3.y * wtk[13] + A3.z * wtk[14] + A3.w * wtk[15];
            float lg = (a0 + a1) + (a2 + a3);
            lg += __shfl_xor(lg, 1, 32);
            lg += __shfl_xor(lg, 2, 32);
            lg += __shfl_xor(lg, 4, 32);   // 8-lane head group holds full logit
            float x = lg + bt;
            x = (x >= 0.f) ? x : LRELU * x;           // leaky_relu
            float p = __expf(x);                      // no max subtraction
            p = valid ? p : 0.f;
            l += p;
            S[0]  += p * A0.x;  S[1]  += p * A0.y;  S[2]  += p * A0.z;  S[3]  += p * A0.w;
            S[4]  += p * A1.x;  S[5]  += p * A1.y;  S[6]  += p * A1.z;  S[7]  += p * A1.w;
            S[8]  += p * A2.x;  S[9]  += p * A2.y;  S[10] += p * A2.z;  S[11] += p * A2.w;
            S[12] += p * A3.x;  S[13] += p * A3.y;  S[14] += p * A3.z;  S[15] += p * A3.w;
        }
        __syncthreads();                              // Vt free for next stage
    }

    // ---- block combine across 8 half-waves (smem reused: Sall/llds)
    if (j == 0) llds[hw * NH + h] = l;
    #pragma unroll
    for (int t = 0; t < 4; ++t) {
        float4 s4;
        s4.x = S[4 * t]; s4.y = S[4 * t + 1]; s4.z = S[4 * t + 2]; s4.w = S[4 * t + 3];
        *reinterpret_cast<float4*>(&Sall[hw][h][16 * j + 4 * t]) = s4;
    }
    __syncthreads();
    // ---- atomic-add merge into per-graph accumulators
    if (tid < 4) {
        float L = 0.f;
        #pragma unroll
        for (int ww = 0; ww < 8; ++ww) L += llds[ww * NH + tid];
        atomicAdd(&Lacc[b * NH + tid], L);
    }
    #pragma unroll
    for (int r2 = 0; r2 < 2; ++r2) {
        const int e = tid + r2 * 256;
        const int hh = e >> 7, k = e & 127;
        float s = 0.f;
        #pragma unroll
        for (int ww = 0; ww < 8; ++ww) s += Sall[ww][hh][k];
        atomicAdd(&Sacc[(size_t)b * HC + e], s);
    }
    __syncthreads();                  // drains vmcnt -> this block's atomics durable
    if (tid == 0) sOld = atomicAdd(&cnt[b], 1);
    __syncthreads();
    if (sOld != NSLICE - 1) return;   // not the last block for this graph

    // ---- winner: coherent re-read of accumulators (atomicAdd(p,0) returns current),
    //      normalize, output GEMV (was k2)
    if (tid < 4) Lh[tid] = atomicAdd(&Lacc[b * NH + tid], 0.f);
    __syncthreads();
    #pragma unroll
    for (int r2 = 0; r2 < 2; ++r2) {
        const int e = tid + r2 * 256;
        const float stot = atomicAdd(&Sacc[(size_t)b * HC + e], 0.f);
        smem[e] = stot / Lh[e >> 7];                  // Sn[h*128+k]
    }
    __syncthreads();
    #pragma unroll
    for (int r2 = 0; r2 < 2; ++r2) {
        const int d = tid + r2 * 256;
        const int hh = d >> 7;
        float acc = 0.f;
        #pragma unroll 4
        for (int k = 0; k < NC; ++k) acc += smem[hh * NC + k] * W[(size_t)k * HC + d];
        out[(size_t)b * HC + d] = acc + bias[d];
    }
}

extern "C" void kernel_launch(void* const* d_in, const int* in_sizes, int n_in,
                              void* d_out, int out_size, void* d_ws, size_t ws_size,
                              hipStream_t stream)
{
    const float* V    = (const float*)d_in[0];
    const int*   gsz  = (const int*)d_in[1];
    const float* W    = (const float*)d_in[2];
    const float* bias = (const float*)d_in[3];
    const float* tune = (const float*)d_in[4];
    float* out = (float*)d_out;
    float* ws  = (float*)d_ws;

    hipLaunchKernelGGL(k0_wt, dim3(NC + 1), dim3(128), 0, stream, W, bias, tune, ws);
    hipLaunchKernelGGL(kfused, dim3(NSLICE, NB), dim3(256), 0, stream, V, gsz, ws, W, bias, out);
}